// Round 10
// baseline (156.797 us; speedup 1.0000x reference)
//
#include <hip/hip_runtime.h>
#include <hip/hip_bf16.h>
#include <hip/hip_cooperative_groups.h>

namespace cg = cooperative_groups;

// Performer FAVOR+ causal attention, MI355X gfx950.
// B=4 H=16 S=1024 D=64 M=64. fp32 in/out, bf16 MFMA internally.
// R10: single cooperative kernel — phase0 {k-dd in regs + q-featmap + vtrans
// + partial kmax}, gridsync, phase1 {kp from regs}, gridsync, phase2 {attn,
// FROZEN text}. Fallback to R9 3-kernel path if coop launch unavailable.

#define NRM 0.35355339059327373f   // 64^-0.25
#define EPSF 1e-4f

typedef __attribute__((ext_vector_type(8))) short short8;
typedef __attribute__((ext_vector_type(4))) float f32x4;
typedef __attribute__((ext_vector_type(4))) unsigned uint4v;
typedef unsigned short u16;

__device__ inline u16 f2bf(float f) {
    unsigned u = __float_as_uint(f);
    return (u16)((u + 0x7FFFu + ((u >> 16) & 1u)) >> 16);   // RNE
}
__device__ inline unsigned cvtpk(float lo, float hi) {
    unsigned r; asm("v_cvt_pk_bf16_f32 %0, %1, %2" : "=v"(r) : "v"(lo), "v"(hi)); return r;
}

// ===========================================================================
// Fused cooperative kernel. 512 blocks x 256 threads, 2 blocks/CU.
// ===========================================================================
__global__ __launch_bounds__(256, 2) void fused(
    const float* __restrict__ q, const float* __restrict__ k,
    const float* __restrict__ v, const float* __restrict__ proj,
    float* __restrict__ pmax,
    u16* __restrict__ qp, u16* __restrict__ kp, u16* __restrict__ vT,
    float* __restrict__ out)
{
    __shared__ union {
        struct { u16 PT[64][72]; u16 tile[64][72]; float red[4]; } p;
        char attn[2][16384];
    } smem;

    const int tid = threadIdx.x, lane = tid & 63, wave = tid >> 6;
    const int l15 = lane & 15, lhi = lane >> 4;
    const int b = blockIdx.x;            // 0..511
    cg::grid_group grid = cg::this_grid();

    // ================= phase 0 =================
    #pragma unroll
    for (int p = 0; p < 4; ++p) {
        int d = p * 16 + (tid >> 4);
        int m = (tid & 15) * 4;
        float4 pv = *(const float4*)(proj + d * 64 + m);
        smem.p.PT[m + 0][d] = f2bf(pv.x);
        smem.p.PT[m + 1][d] = f2bf(pv.y);
        smem.p.PT[m + 2][d] = f2bf(pv.z);
        smem.p.PT[m + 3][d] = f2bf(pv.w);
    }
    __syncthreads();

    const int sA = b * 8 + wave * 2;     // this wave's strips (k and q)
    const int sB = sA + 1;

    // ---- k dd-GEMM, kept in registers across the grid sync
    f32x4 cA[4] = {{0,0,0,0},{0,0,0,0},{0,0,0,0},{0,0,0,0}};
    f32x4 cB[4] = {{0,0,0,0},{0,0,0,0},{0,0,0,0},{0,0,0,0}};
    float diagA[4], diagB[4];
    float m2 = -INFINITY;

#define KSTRIP(SS, CC, DD)                                                      \
    {                                                                           \
        const int row0 = (SS) * 16;                                             \
        const float* xs = k + (size_t)(row0 + l15) * 64 + lhi * 8;              \
        float4 f0 = *(const float4*)(xs);                                       \
        float4 f1 = *(const float4*)(xs + 4);                                   \
        float4 f2 = *(const float4*)(xs + 32);                                  \
        float4 f3 = *(const float4*)(xs + 36);                                  \
        short8 a0, a1;                                                          \
        a0[0]=(short)f2bf(f0.x); a0[1]=(short)f2bf(f0.y);                       \
        a0[2]=(short)f2bf(f0.z); a0[3]=(short)f2bf(f0.w);                       \
        a0[4]=(short)f2bf(f1.x); a0[5]=(short)f2bf(f1.y);                       \
        a0[6]=(short)f2bf(f1.z); a0[7]=(short)f2bf(f1.w);                       \
        a1[0]=(short)f2bf(f2.x); a1[1]=(short)f2bf(f2.y);                       \
        a1[2]=(short)f2bf(f2.z); a1[3]=(short)f2bf(f2.w);                       \
        a1[4]=(short)f2bf(f3.x); a1[5]=(short)f2bf(f3.y);                       \
        a1[6]=(short)f2bf(f3.z); a1[7]=(short)f2bf(f3.w);                       \
        float ss = f0.x*f0.x + f0.y*f0.y + f0.z*f0.z + f0.w*f0.w                \
                 + f1.x*f1.x + f1.y*f1.y + f1.z*f1.z + f1.w*f1.w                \
                 + f2.x*f2.x + f2.y*f2.y + f2.z*f2.z + f2.w*f2.w                \
                 + f3.x*f3.x + f3.y*f3.y + f3.z*f3.z + f3.w*f3.w;               \
        ss += __shfl_xor(ss, 16);                                               \
        ss += __shfl_xor(ss, 32);                                               \
        _Pragma("unroll")                                                       \
        for (int ct = 0; ct < 4; ++ct) {                                        \
            short8 b0 = *(const short8*)&smem.p.PT[ct*16 + l15][lhi*8];         \
            short8 b1 = *(const short8*)&smem.p.PT[ct*16 + l15][32 + lhi*8];    \
            CC[ct] = __builtin_amdgcn_mfma_f32_16x16x32_bf16(a0, b0, CC[ct],0,0,0); \
            CC[ct] = __builtin_amdgcn_mfma_f32_16x16x32_bf16(a1, b1, CC[ct],0,0,0); \
        }                                                                       \
        _Pragma("unroll")                                                       \
        for (int r = 0; r < 4; ++r) DD[r] = __shfl(ss, lhi * 4 + r) * 0.0625f;  \
        _Pragma("unroll")                                                       \
        for (int ct = 0; ct < 4; ++ct)                                          \
            m2 = fmaxf(m2, fmaxf(fmaxf(CC[ct][0], CC[ct][1]),                   \
                                 fmaxf(CC[ct][2], CC[ct][3])));                 \
    }
    KSTRIP(sA, cA, diagA)
    KSTRIP(sB, cB, diagB)
#undef KSTRIP

    m2 = fmaxf(m2, __shfl_xor(m2, 1));
    m2 = fmaxf(m2, __shfl_xor(m2, 2));
    m2 = fmaxf(m2, __shfl_xor(m2, 4));
    m2 = fmaxf(m2, __shfl_xor(m2, 8));
    m2 = fmaxf(m2, __shfl_xor(m2, 16));
    m2 = fmaxf(m2, __shfl_xor(m2, 32));
    if (lane == 0) smem.p.red[wave] = m2 * NRM;

    // ---- q featmap for the same 2 strips (independent of k path)
    for (int i = 0; i < 2; ++i) {
        const int strip = sA + i;
        const int row0  = strip * 16;
        const float* xs = q + (size_t)(row0 + l15) * 64 + lhi * 8;
        float4 f0 = *(const float4*)(xs);
        float4 f1 = *(const float4*)(xs + 4);
        float4 f2 = *(const float4*)(xs + 32);
        float4 f3 = *(const float4*)(xs + 36);

        short8 a0, a1;
        a0[0] = (short)f2bf(f0.x); a0[1] = (short)f2bf(f0.y);
        a0[2] = (short)f2bf(f0.z); a0[3] = (short)f2bf(f0.w);
        a0[4] = (short)f2bf(f1.x); a0[5] = (short)f2bf(f1.y);
        a0[6] = (short)f2bf(f1.z); a0[7] = (short)f2bf(f1.w);
        a1[0] = (short)f2bf(f2.x); a1[1] = (short)f2bf(f2.y);
        a1[2] = (short)f2bf(f2.z); a1[3] = (short)f2bf(f2.w);
        a1[4] = (short)f2bf(f3.x); a1[5] = (short)f2bf(f3.y);
        a1[6] = (short)f2bf(f3.z); a1[7] = (short)f2bf(f3.w);

        float ss = f0.x*f0.x + f0.y*f0.y + f0.z*f0.z + f0.w*f0.w
                 + f1.x*f1.x + f1.y*f1.y + f1.z*f1.z + f1.w*f1.w
                 + f2.x*f2.x + f2.y*f2.y + f2.z*f2.z + f2.w*f2.w
                 + f3.x*f3.x + f3.y*f3.y + f3.z*f3.z + f3.w*f3.w;
        ss += __shfl_xor(ss, 16);
        ss += __shfl_xor(ss, 32);

        f32x4 c[4] = { {0,0,0,0}, {0,0,0,0}, {0,0,0,0}, {0,0,0,0} };
        #pragma unroll
        for (int ct = 0; ct < 4; ++ct) {
            short8 b0 = *(const short8*)&smem.p.PT[ct * 16 + l15][lhi * 8];
            short8 b1 = *(const short8*)&smem.p.PT[ct * 16 + l15][32 + lhi * 8];
            c[ct] = __builtin_amdgcn_mfma_f32_16x16x32_bf16(a0, b0, c[ct], 0, 0, 0);
            c[ct] = __builtin_amdgcn_mfma_f32_16x16x32_bf16(a1, b1, c[ct], 0, 0, 0);
        }

        float diag[4];
        #pragma unroll
        for (int r = 0; r < 4; ++r) diag[r] = __shfl(ss, lhi * 4 + r) * 0.0625f;

        float mx[4];
        #pragma unroll
        for (int r = 0; r < 4; ++r)
            mx[r] = fmaxf(fmaxf(c[0][r], c[1][r]), fmaxf(c[2][r], c[3][r]));
        #pragma unroll
        for (int r = 0; r < 4; ++r) {
            float m = mx[r];
            m = fmaxf(m, __shfl_xor(m, 1));
            m = fmaxf(m, __shfl_xor(m, 2));
            m = fmaxf(m, __shfl_xor(m, 4));
            m = fmaxf(m, __shfl_xor(m, 8));
            mx[r] = m;
        }
        u16* op = qp + (size_t)row0 * 64;
        #pragma unroll
        for (int ct = 0; ct < 4; ++ct) {
            #pragma unroll
            for (int r = 0; r < 4; ++r) {
                float val = __expf(c[ct][r] * NRM - diag[r] - mx[r] * NRM) + EPSF;
                op[(lhi * 4 + r) * 64 + ct * 16 + l15] = f2bf(val);
            }
        }
    }

    __syncthreads();
    if (tid == 0)
        pmax[b] = fmaxf(fmaxf(smem.p.red[0], smem.p.red[1]),
                        fmaxf(smem.p.red[2], smem.p.red[3]));

    // ---- v transpose, 2 tiles per block
    for (int i = 0; i < 2; ++i) {
        const int t = b * 2 + i;               // 0..1023
        const int bh = t >> 4, s0 = (t & 15) << 6;
        const float* src = v + ((size_t)bh * 1024 + s0) * 64;
        #pragma unroll
        for (int p = 0; p < 4; ++p) {
            int s = p * 16 + (tid >> 4);
            int d = (tid & 15) * 4;
            float4 val = *(const float4*)(src + s * 64 + d);
            smem.p.tile[d + 0][s] = f2bf(val.x);
            smem.p.tile[d + 1][s] = f2bf(val.y);
            smem.p.tile[d + 2][s] = f2bf(val.z);
            smem.p.tile[d + 3][s] = f2bf(val.w);
        }
        __syncthreads();
        u16* dst = vT + (size_t)bh * 65536 + s0;
        #pragma unroll
        for (int p = 0; p < 4; ++p) {
            int d = p * 16 + (tid >> 4);
            int s = (tid & 15) * 4;
            ushort4 o;
            o.x = smem.p.tile[d][s];     o.y = smem.p.tile[d][s + 1];
            o.z = smem.p.tile[d][s + 2]; o.w = smem.p.tile[d][s + 3];
            *(ushort4*)(dst + d * 1024 + s) = o;
        }
        __syncthreads();   // WAR: tile reused next iteration
    }

    grid.sync();

    // ================= phase 1: kp from register dd =================
    {
        const int hb = b >> 3;
        const float* pb = pmax + hb * 8;
        float stab = fmaxf(fmaxf(fmaxf(pb[0], pb[1]), fmaxf(pb[2], pb[3])),
                           fmaxf(fmaxf(pb[4], pb[5]), fmaxf(pb[6], pb[7])));
#define KPOUT(SS, CC, DD)                                                       \
        {                                                                       \
            u16* op = kp + (size_t)((SS) * 16) * 64;                            \
            _Pragma("unroll")                                                   \
            for (int ct = 0; ct < 4; ++ct) {                                    \
                _Pragma("unroll")                                               \
                for (int r = 0; r < 4; ++r) {                                   \
                    float val = __expf(CC[ct][r] * NRM - DD[r] - stab) + EPSF;  \
                    op[(lhi * 4 + r) * 64 + ct * 16 + l15] = f2bf(val);         \
                }                                                               \
            }                                                                   \
        }
        KPOUT(sA, cA, diagA)
        KPOUT(sB, cB, diagB)
#undef KPOUT
    }

    grid.sync();

    // ================= phase 2: attn (FROZEN R3/R5/R7/R8/R9 text) ==========
    {
    char (*lds)[16384] = smem.attn;

    const int x = blockIdx.x;
    const int h = (((x >> 6) << 3)) | (x & 7);   // head: 8 blocks/head on one XCD
    const int j = (x >> 3) & 7;                  // 0..7

    const u16* kph = kp + (size_t)h * 65536;
    const u16* vTh = vT + (size_t)h * 65536;

    const int rch = lane >> 3;            // row within 8-row chunk
    const int cb  = (lane & 7) * 16;      // col byte within 128B row
    const bool isK = wave < 2;
    const int cbase = (wave & 1) * 4;
    const int gstride = isK ? 4096 : 64;  // elements per kt step

    int lo0, lo1, lo2, lo3;
    const u16 *go0, *go1, *go2, *go3;
    {
        #define STG(cc, LO, GO)                                                 \
        {   int i = cbase + cc; int row = 8 * i + rch;                          \
            int nib = (row & 3) | (((row >> 3) & 1) << 2);                      \
            LO = (isK ? 0 : 8192) + row * 128 + (cb ^ (nib << 4));              \
            GO = isK ? (kph + row * 64 + (cb >> 1))                             \
                     : (vTh + (size_t)row * 1024 + (cb >> 1)); }
        STG(0, lo0, go0) STG(1, lo1, go1) STG(2, lo2, go2) STG(3, lo3, go3)
        #undef STG
    }

    const int rowp = 8 * (l15 >> 2) + (l15 & 3);
    const int nk = (l15 & 3) | (((l15 >> 2) & 1) << 2);
    const int nv = (l15 & 3) | (((l15 >> 3) & 1) << 2);
    const int ok0 = rowp * 128 + ((16 * lhi) ^ (nk << 4));
    const int ok1 = rowp * 128 + ((64 + 16 * lhi) ^ (nk << 4));
    const int ov0 = 8192 + l15 * 128 + ((16 * lhi) ^ (nv << 4));
    const int ov1 = 8192 + l15 * 128 + ((64 + 16 * lhi) ^ (nv << 4));

    short8 ls0, ls1, ls2, ls3;   // staging registers

    auto stageLoad = [&](int kt) {
        ls0 = *(const short8*)(go0 + (size_t)kt * gstride);
        ls1 = *(const short8*)(go1 + (size_t)kt * gstride);
        ls2 = *(const short8*)(go2 + (size_t)kt * gstride);
        ls3 = *(const short8*)(go3 + (size_t)kt * gstride);
    };
    auto stageWrite = [&](char* B) {
        *(short8*)(B + lo0) = ls0;
        *(short8*)(B + lo1) = ls1;
        *(short8*)(B + lo2) = ls2;
        *(short8*)(B + lo3) = ls3;
    };

    auto runStrip = [&](int sigma, int T) {
        const u16* qpr = qp + ((size_t)h * 1024 + sigma * 16 + l15) * 64 + lhi * 8;
        short8 aq0 = *(const short8*)(qpr);
        short8 aq1 = *(const short8*)(qpr + 32);
        const int qrl = ((sigma & 3) << 4) + l15;   // local q-row in diag tile

        f32x4 acc0 = {0,0,0,0}, acc1 = {0,0,0,0}, acc2 = {0,0,0,0}, acc3 = {0,0,0,0};
        float den = 0.f;

        stageLoad(0);
        stageWrite(lds[0]);
        __syncthreads();

        int cur = 0;
        for (int kt = 0; kt <= T; ++kt) {
            if (kt < T) stageLoad(kt + 1);

            const char* B = lds[cur];
            short8 k0 = *(const short8*)(B + ok0);
            short8 k1 = *(const short8*)(B + ok1);
            short8 k2 = *(const short8*)(B + ok0 + 512);
            short8 k3 = *(const short8*)(B + ok1 + 512);
            short8 k4 = *(const short8*)(B + ok0 + 4096);
            short8 k5 = *(const short8*)(B + ok1 + 4096);
            short8 k6 = *(const short8*)(B + ok0 + 4608);
            short8 k7 = *(const short8*)(B + ok1 + 4608);
            short8 v0 = *(const short8*)(B + ov0);
            short8 v1 = *(const short8*)(B + ov1);
            short8 v2 = *(const short8*)(B + ov0 + 2048);
            short8 v3 = *(const short8*)(B + ov1 + 2048);
            short8 v4 = *(const short8*)(B + ov0 + 4096);
            short8 v5 = *(const short8*)(B + ov1 + 4096);
            short8 v6 = *(const short8*)(B + ov0 + 6144);
            short8 v7 = *(const short8*)(B + ov1 + 6144);

            f32x4 s0 = {0,0,0,0}, s1 = {0,0,0,0}, s2 = {0,0,0,0}, s3 = {0,0,0,0};
            __builtin_amdgcn_s_setprio(1);
            s0 = __builtin_amdgcn_mfma_f32_16x16x32_bf16(k0, aq0, s0, 0, 0, 0);
            s0 = __builtin_amdgcn_mfma_f32_16x16x32_bf16(k1, aq1, s0, 0, 0, 0);
            s1 = __builtin_amdgcn_mfma_f32_16x16x32_bf16(k2, aq0, s1, 0, 0, 0);
            s1 = __builtin_amdgcn_mfma_f32_16x16x32_bf16(k3, aq1, s1, 0, 0, 0);
            s2 = __builtin_amdgcn_mfma_f32_16x16x32_bf16(k4, aq0, s2, 0, 0, 0);
            s2 = __builtin_amdgcn_mfma_f32_16x16x32_bf16(k5, aq1, s2, 0, 0, 0);
            s3 = __builtin_amdgcn_mfma_f32_16x16x32_bf16(k6, aq0, s3, 0, 0, 0);
            s3 = __builtin_amdgcn_mfma_f32_16x16x32_bf16(k7, aq1, s3, 0, 0, 0);
            __builtin_amdgcn_s_setprio(0);

            if (kt == T) {   // diagonal-tile causal mask
                const int kc = 8 * lhi;
                #pragma unroll
                for (int r = 0; r < 4; ++r) {
                    if (kc + r      > qrl) s0[r] = 0.f;
                    if (kc + 4 + r  > qrl) s1[r] = 0.f;
                    if (kc + 32 + r > qrl) s2[r] = 0.f;
                    if (kc + 36 + r > qrl) s3[r] = 0.f;
                }
            }
            float t0 = (s0[0] + s0[1]) + (s0[2] + s0[3]);
            float t1 = (s1[0] + s1[1]) + (s1[2] + s1[3]);
            float t2 = (s2[0] + s2[1]) + (s2[2] + s2[3]);
            float t3 = (s3[0] + s3[1]) + (s3[2] + s3[3]);
            den += (t0 + t1) + (t2 + t3);

            uint4v w0 = { cvtpk(s0[0], s0[1]), cvtpk(s0[2], s0[3]),
                          cvtpk(s1[0], s1[1]), cvtpk(s1[2], s1[3]) };
            uint4v w1 = { cvtpk(s2[0], s2[1]), cvtpk(s2[2], s2[3]),
                          cvtpk(s3[0], s3[1]), cvtpk(s3[2], s3[3]) };
            short8 pa0 = __builtin_bit_cast(short8, w0);
            short8 pa1 = __builtin_bit_cast(short8, w1);

            __builtin_amdgcn_s_setprio(1);
            acc0 = __builtin_amdgcn_mfma_f32_16x16x32_bf16(pa0, v0, acc0, 0, 0, 0);
            acc0 = __builtin_amdgcn_mfma_f32_16x16x32_bf16(pa1, v1, acc0, 0, 0, 0);
            acc1 = __builtin_amdgcn_mfma_f32_16x16x32_bf16(pa0, v2, acc1, 0, 0, 0);
            acc1 = __builtin_amdgcn_mfma_f32_16x16x32_bf16(pa1, v3, acc1, 0, 0, 0);
            acc2 = __builtin_amdgcn_mfma_f32_16x16x32_bf16(pa0, v4, acc2, 0, 0, 0);
            acc2 = __builtin_amdgcn_mfma_f32_16x16x32_bf16(pa1, v5, acc2, 0, 0, 0);
            acc3 = __builtin_amdgcn_mfma_f32_16x16x32_bf16(pa0, v6, acc3, 0, 0, 0);
            acc3 = __builtin_amdgcn_mfma_f32_16x16x32_bf16(pa1, v7, acc3, 0, 0, 0);
            __builtin_amdgcn_s_setprio(0);

            if (kt < T) stageWrite(lds[cur ^ 1]);   // vmcnt wait lands here
            __syncthreads();
            cur ^= 1;
        }

        den += __shfl_xor(den, 16);
        den += __shfl_xor(den, 32);
        float inv[4];
        #pragma unroll
        for (int r = 0; r < 4; ++r) inv[r] = 1.0f / __shfl(den, lhi * 4 + r);

        float* ob = out + ((size_t)h * 1024 + sigma * 16) * 64;
        #pragma unroll
        for (int r = 0; r < 4; ++r) {
            ob[(lhi * 4 + r) * 64 +  0 + l15] = acc0[r] * inv[r];
            ob[(lhi * 4 + r) * 64 + 16 + l15] = acc1[r] * inv[r];
            ob[(lhi * 4 + r) * 64 + 32 + l15] = acc2[r] * inv[r];
            ob[(lhi * 4 + r) * 64 + 48 + l15] = acc3[r] * inv[r];
        }
    };

    const int s0v = 4 * j + wave;     // 0..31, T = j (uniform in block)
    runStrip(s0v, j);
    runStrip(63 - s0v, 15 - j);       // T = 15-j (uniform in block)
    }
}

// ===========================================================================
// Fallback path (R9, proven): kmax + prep + attn as separate kernels.
// ===========================================================================
__global__ __launch_bounds__(256) void kmax9(
    const float* __restrict__ k, const float* __restrict__ proj,
    float* __restrict__ pmax, u16* __restrict__ ptg)
{
    __shared__ u16 PT[64][72];
    __shared__ float red[4];
    const int tid = threadIdx.x, lane = tid & 63, wave = tid >> 6;
    const int l15 = lane & 15, lhi = lane >> 4;
    const int b = blockIdx.x;   // 0..255

    #pragma unroll
    for (int p = 0; p < 4; ++p) {
        int d = p * 16 + (tid >> 4);
        int m = (tid & 15) * 4;
        float4 pv = *(const float4*)(proj + d * 64 + m);
        PT[m + 0][d] = f2bf(pv.x);
        PT[m + 1][d] = f2bf(pv.y);
        PT[m + 2][d] = f2bf(pv.z);
        PT[m + 3][d] = f2bf(pv.w);
    }
    __syncthreads();

    if (b == 0) {
        const int m = tid >> 2, c0 = (tid & 3) * 16;
        short8 x0 = *(const short8*)&PT[m][c0];
        short8 x1 = *(const short8*)&PT[m][c0 + 8];
        *(short8*)(ptg + m * 64 + c0)     = x0;
        *(short8*)(ptg + m * 64 + c0 + 8) = x1;
    }

    float m2 = -INFINITY;
    for (int i = 0; i < 4; ++i) {
        const int strip = b * 16 + wave * 4 + i;
        const int row0  = strip * 16;
        const float* xs = k + (size_t)(row0 + l15) * 64 + lhi * 8;
        float4 f0 = *(const float4*)(xs);
        float4 f1 = *(const float4*)(xs + 4);
        float4 f2 = *(const float4*)(xs + 32);
        float4 f3 = *(const float4*)(xs + 36);

        short8 a0, a1;
        a0[0] = (short)f2bf(f0.x); a0[1] = (short)f2bf(f0.y);
        a0[2] = (short)f2bf(f0.z); a0[3] = (short)f2bf(f0.w);
        a0[4] = (short)f2bf(f1.x); a0[5] = (short)f2bf(f1.y);
        a0[6] = (short)f2bf(f1.z); a0[7] = (short)f2bf(f1.w);
        a1[0] = (short)f2bf(f2.x); a1[1] = (short)f2bf(f2.y);
        a1[2] = (short)f2bf(f2.z); a1[3] = (short)f2bf(f2.w);
        a1[4] = (short)f2bf(f3.x); a1[5] = (short)f2bf(f3.y);
        a1[6] = (short)f2bf(f3.z); a1[7] = (short)f2bf(f3.w);

        f32x4 c[4] = { {0,0,0,0}, {0,0,0,0}, {0,0,0,0}, {0,0,0,0} };
        #pragma unroll
        for (int ct = 0; ct < 4; ++ct) {
            short8 b0 = *(const short8*)&PT[ct * 16 + l15][lhi * 8];
            short8 b1 = *(const short8*)&PT[ct * 16 + l15][32 + lhi * 8];
            c[ct] = __builtin_amdgcn_mfma_f32_16x16x32_bf16(a0, b0, c[ct], 0, 0, 0);
            c[ct] = __builtin_amdgcn_mfma_f32_16x16x32_bf16(a1, b1, c[ct], 0, 0, 0);
        }
        #pragma unroll
        for (int ct = 0; ct < 4; ++ct) {
            m2 = fmaxf(m2, fmaxf(fmaxf(c[ct][0], c[ct][1]), fmaxf(c[ct][2], c[ct][3])));
        }
    }
    m2 = fmaxf(m2, __shfl_xor(m2, 1));
    m2 = fmaxf(m2, __shfl_xor(m2, 2));
    m2 = fmaxf(m2, __shfl_xor(m2, 4));
    m2 = fmaxf(m2, __shfl_xor(m2, 8));
    m2 = fmaxf(m2, __shfl_xor(m2, 16));
    m2 = fmaxf(m2, __shfl_xor(m2, 32));
    if (lane == 0) red[wave] = m2 * NRM;
    __syncthreads();
    if (tid == 0)
        pmax[b] = fmaxf(fmaxf(red[0], red[1]), fmaxf(red[2], red[3]));
}

__global__ __launch_bounds__(256) void prep9(
    const float* __restrict__ q, const float* __restrict__ k,
    const float* __restrict__ v, const u16* __restrict__ ptg,
    const float* __restrict__ pmax,
    u16* __restrict__ qp, u16* __restrict__ kp, u16* __restrict__ vT)
{
    __shared__ u16 tile[64][72];
    const int tid = threadIdx.x, lane = tid & 63, wave = tid >> 6;
    const int l15 = lane & 15, lhi = lane >> 4;
    const int bid = blockIdx.x;

    if (bid >= 512) {
        const int vb = bid - 512;
        for (int i = 0; i < 4; ++i) {
            const int t = vb * 4 + i;
            const int bh = t >> 4, s0 = (t & 15) << 6;
            const float* src = v + ((size_t)bh * 1024 + s0) * 64;
            #pragma unroll
            for (int p = 0; p < 4; ++p) {
                int s = p * 16 + (tid >> 4);
                int d = (tid & 15) * 4;
                float4 val = *(const float4*)(src + s * 64 + d);
                tile[d + 0][s] = f2bf(val.x);
                tile[d + 1][s] = f2bf(val.y);
                tile[d + 2][s] = f2bf(val.z);
                tile[d + 3][s] = f2bf(val.w);
            }
            __syncthreads();
            u16* dst = vT + (size_t)bh * 65536 + s0;
            #pragma unroll
            for (int p = 0; p < 4; ++p) {
                int d = p * 16 + (tid >> 4);
                int s = (tid & 15) * 4;
                ushort4 o;
                o.x = tile[d][s]; o.y = tile[d][s + 1];
                o.z = tile[d][s + 2]; o.w = tile[d][s + 3];
                *(ushort4*)(dst + d * 1024 + s) = o;
            }
            __syncthreads();
        }
        return;
    }

    const bool isQ = bid < 256;
    const float* x = isQ ? q : k;
    const int bid2 = bid & 255;

    short8 bf0[4], bf1[4];
    #pragma unroll
    for (int ct = 0; ct < 4; ++ct) {
        const u16* pr = ptg + (ct * 16 + l15) * 64 + lhi * 8;
        bf0[ct] = *(const short8*)(pr);
        bf1[ct] = *(const short8*)(pr + 32);
    }

    float stab = 0.f;
    if (!isQ) {
        const int h = bid2 >> 2;
        const float* pb = pmax + h * 4;
        stab = fmaxf(fmaxf(pb[0], pb[1]), fmaxf(pb[2], pb[3]));
    }

    for (int i = 0; i < 4; ++i) {
        const int strip = bid2 * 16 + wave * 4 + i;
        const int row0  = strip * 16;

        const float* xs = x + (size_t)(row0 + l15) * 64 + lhi * 8;
        float4 f0 = *(const float4*)(xs);
        float4 f1 = *(const float4*)(xs + 4);
        float4 f2 = *(const float4*)(xs + 32);
        float4 f3 = *(const float4*)(xs + 36);

        short8 a0, a1;
        a0[0] = (short)f2bf(f0.x); a0[1] = (short)f2bf(f0.y);
        a0[2] = (short)f2bf(f0.z); a0[3] = (short)f2bf(f0.w);
        a0[4] = (short)f2bf(f1.x); a0[5] = (short)f2bf(f1.y);
        a0[6] = (short)f2bf(f1.z); a0[7] = (short)f2bf(f1.w);
        a1[0] = (short)f2bf(f2.x); a1[1] = (short)f2bf(f2.y);
        a1[2] = (short)f2bf(f2.z); a1[3] = (short)f2bf(f2.w);
        a1[4] = (short)f2bf(f3.x); a1[5] = (short)f2bf(f3.y);
        a1[6] = (short)f2bf(f3.z); a1[7] = (short)f2bf(f3.w);

        float ss = f0.x*f0.x + f0.y*f0.y + f0.z*f0.z + f0.w*f0.w
                 + f1.x*f1.x + f1.y*f1.y + f1.z*f1.z + f1.w*f1.w
                 + f2.x*f2.x + f2.y*f2.y + f2.z*f2.z + f2.w*f2.w
                 + f3.x*f3.x + f3.y*f3.y + f3.z*f3.z + f3.w*f3.w;
        ss += __shfl_xor(ss, 16);
        ss += __shfl_xor(ss, 32);

        f32x4 c[4] = { {0,0,0,0}, {0,0,0,0}, {0,0,0,0}, {0,0,0,0} };
        #pragma unroll
        for (int ct = 0; ct < 4; ++ct) {
            c[ct] = __builtin_amdgcn_mfma_f32_16x16x32_bf16(a0, bf0[ct], c[ct], 0, 0, 0);
            c[ct] = __builtin_amdgcn_mfma_f32_16x16x32_bf16(a1, bf1[ct], c[ct], 0, 0, 0);
        }

        float diag[4];
        #pragma unroll
        for (int r = 0; r < 4; ++r) diag[r] = __shfl(ss, lhi * 4 + r) * 0.0625f;

        if (isQ) {
            float mx[4];
            #pragma unroll
            for (int r = 0; r < 4; ++r)
                mx[r] = fmaxf(fmaxf(c[0][r], c[1][r]), fmaxf(c[2][r], c[3][r]));
            #pragma unroll
            for (int r = 0; r < 4; ++r) {
                float m = mx[r];
                m = fmaxf(m, __shfl_xor(m, 1));
                m = fmaxf(m, __shfl_xor(m, 2));
                m = fmaxf(m, __shfl_xor(m, 4));
                m = fmaxf(m, __shfl_xor(m, 8));
                mx[r] = m;
            }
            u16* op = qp + (size_t)row0 * 64;
            #pragma unroll
            for (int ct = 0; ct < 4; ++ct) {
                #pragma unroll
                for (int r = 0; r < 4; ++r) {
                    float val = __expf(c[ct][r] * NRM - diag[r] - mx[r] * NRM) + EPSF;
                    op[(lhi * 4 + r) * 64 + ct * 16 + l15] = f2bf(val);
                }
            }
        } else {
            u16* op = kp + (size_t)row0 * 64;
            #pragma unroll
            for (int ct = 0; ct < 4; ++ct) {
                #pragma unroll
                for (int r = 0; r < 4; ++r) {
                    float val = __expf(c[ct][r] * NRM - diag[r] - stab) + EPSF;
                    op[(lhi * 4 + r) * 64 + ct * 16 + l15] = f2bf(val);
                }
            }
        }
    }
}

__global__ __launch_bounds__(256, 2) void attn9(
    const u16* __restrict__ qp, const u16* __restrict__ kp,
    const u16* __restrict__ vT, float* __restrict__ out)
{
    __shared__ char lds[2][16384];

    const int tid = threadIdx.x, lane = tid & 63, wave = tid >> 6;
    const int l15 = lane & 15, lhi = lane >> 4;
    const int x = blockIdx.x;
    const int h = (((x >> 6) << 3)) | (x & 7);
    const int j = (x >> 3) & 7;

    const u16* kph = kp + (size_t)h * 65536;
    const u16* vTh = vT + (size_t)h * 65536;

    const int rch = lane >> 3;
    const int cb  = (lane & 7) * 16;
    const bool isK = wave < 2;
    const int cbase = (wave & 1) * 4;
    const int gstride = isK ? 4096 : 64;

    int lo0, lo1, lo2, lo3;
    const u16 *go0, *go1, *go2, *go3;
    {
        #define STG(cc, LO, GO)                                                 \
        {   int i = cbase + cc; int row = 8 * i + rch;                          \
            int nib = (row & 3) | (((row >> 3) & 1) << 2);                      \
            LO = (isK ? 0 : 8192) + row * 128 + (cb ^ (nib << 4));              \
            GO = isK ? (kph + row * 64 + (cb >> 1))                             \
                     : (vTh + (size_t)row * 1024 + (cb >> 1)); }
        STG(0, lo0, go0) STG(1, lo1, go1) STG(2, lo2, go2) STG(3, lo3, go3)
        #undef STG
    }

    const int rowp = 8 * (l15 >> 2) + (l15 & 3);
    const int nk = (l15 & 3) | (((l15 >> 2) & 1) << 2);
    const int nv = (l15 & 3) | (((l15 >> 3) & 1) << 2);
    const int ok0 = rowp * 128 + ((16 * lhi) ^ (nk << 4));
    const int ok1 = rowp * 128 + ((64 + 16 * lhi) ^ (nk << 4));
    const int ov0 = 8192 + l15 * 128 + ((16 * lhi) ^ (nv << 4));
    const int ov1 = 8192 + l15 * 128 + ((64 + 16 * lhi) ^ (nv << 4));

    short8 ls0, ls1, ls2, ls3;

    auto stageLoad = [&](int kt) {
        ls0 = *(const short8*)(go0 + (size_t)kt * gstride);
        ls1 = *(const short8*)(go1 + (size_t)kt * gstride);
        ls2 = *(const short8*)(go2 + (size_t)kt * gstride);
        ls3 = *(const short8*)(go3 + (size_t)kt * gstride);
    };
    auto stageWrite = [&](char* B) {
        *(short8*)(B + lo0) = ls0;
        *(short8*)(B + lo1) = ls1;
        *(short8*)(B + lo2) = ls2;
        *(short8*)(B + lo3) = ls3;
    };

    auto runStrip = [&](int sigma, int T) {
        const u16* qpr = qp + ((size_t)h * 1024 + sigma * 16 + l15) * 64 + lhi * 8;
        short8 aq0 = *(const short8*)(qpr);
        short8 aq1 = *(const short8*)(qpr + 32);
        const int qrl = ((sigma & 3) << 4) + l15;

        f32x4 acc0 = {0,0,0,0}, acc1 = {0,0,0,0}, acc2 = {0,0,0,0}, acc3 = {0,0,0,0};
        float den = 0.f;

        stageLoad(0);
        stageWrite(lds[0]);
        __syncthreads();

        int cur = 0;
        for (int kt = 0; kt <= T; ++kt) {
            if (kt < T) stageLoad(kt + 1);

            const char* B = lds[cur];
            short8 k0 = *(const short8*)(B + ok0);
            short8 k1 = *(const short8*)(B + ok1);
            short8 k2 = *(const short8*)(B + ok0 + 512);
            short8 k3 = *(const short8*)(B + ok1 + 512);
            short8 k4 = *(const short8*)(B + ok0 + 4096);
            short8 k5 = *(const short8*)(B + ok1 + 4096);
            short8 k6 = *(const short8*)(B + ok0 + 4608);
            short8 k7 = *(const short8*)(B + ok1 + 4608);
            short8 v0 = *(const short8*)(B + ov0);
            short8 v1 = *(const short8*)(B + ov1);
            short8 v2 = *(const short8*)(B + ov0 + 2048);
            short8 v3 = *(const short8*)(B + ov1 + 2048);
            short8 v4 = *(const short8*)(B + ov0 + 4096);
            short8 v5 = *(const short8*)(B + ov1 + 4096);
            short8 v6 = *(const short8*)(B + ov0 + 6144);
            short8 v7 = *(const short8*)(B + ov1 + 6144);

            f32x4 s0 = {0,0,0,0}, s1 = {0,0,0,0}, s2 = {0,0,0,0}, s3 = {0,0,0,0};
            __builtin_amdgcn_s_setprio(1);
            s0 = __builtin_amdgcn_mfma_f32_16x16x32_bf16(k0, aq0, s0, 0, 0, 0);
            s0 = __builtin_amdgcn_mfma_f32_16x16x32_bf16(k1, aq1, s0, 0, 0, 0);
            s1 = __builtin_amdgcn_mfma_f32_16x16x32_bf16(k2, aq0, s1, 0, 0, 0);
            s1 = __builtin_amdgcn_mfma_f32_16x16x32_bf16(k3, aq1, s1, 0, 0, 0);
            s2 = __builtin_amdgcn_mfma_f32_16x16x32_bf16(k4, aq0, s2, 0, 0, 0);
            s2 = __builtin_amdgcn_mfma_f32_16x16x32_bf16(k5, aq1, s2, 0, 0, 0);
            s3 = __builtin_amdgcn_mfma_f32_16x16x32_bf16(k6, aq0, s3, 0, 0, 0);
            s3 = __builtin_amdgcn_mfma_f32_16x16x32_bf16(k7, aq1, s3, 0, 0, 0);
            __builtin_amdgcn_s_setprio(0);

            if (kt == T) {
                const int kc = 8 * lhi;
                #pragma unroll
                for (int r = 0; r < 4; ++r) {
                    if (kc + r      > qrl) s0[r] = 0.f;
                    if (kc + 4 + r  > qrl) s1[r] = 0.f;
                    if (kc + 32 + r > qrl) s2[r] = 0.f;
                    if (kc + 36 + r > qrl) s3[r] = 0.f;
                }
            }
            float t0 = (s0[0] + s0[1]) + (s0[2] + s0[3]);
            float t1 = (s1[0] + s1[1]) + (s1[2] + s1[3]);
            float t2 = (s2[0] + s2[1]) + (s2[2] + s2[3]);
            float t3 = (s3[0] + s3[1]) + (s3[2] + s3[3]);
            den += (t0 + t1) + (t2 + t3);

            uint4v w0 = { cvtpk(s0[0], s0[1]), cvtpk(s0[2], s0[3]),
                          cvtpk(s1[0], s1[1]), cvtpk(s1[2], s1[3]) };
            uint4v w1 = { cvtpk(s2[0], s2[1]), cvtpk(s2[2], s2[3]),
                          cvtpk(s3[0], s3[1]), cvtpk(s3[2], s3[3]) };
            short8 pa0 = __builtin_bit_cast(short8, w0);
            short8 pa1 = __builtin_bit_cast(short8, w1);

            __builtin_amdgcn_s_setprio(1);
            acc0 = __builtin_amdgcn_mfma_f32_16x16x32_bf16(pa0, v0, acc0, 0, 0, 0);
            acc0 = __builtin_amdgcn_mfma_f32_16x16x32_bf16(pa1, v1, acc0, 0, 0, 0);
            acc1 = __builtin_amdgcn_mfma_f32_16x16x32_bf16(pa0, v2, acc1, 0, 0, 0);
            acc1 = __builtin_amdgcn_mfma_f32_16x16x32_bf16(pa1, v3, acc1, 0, 0, 0);
            acc2 = __builtin_amdgcn_mfma_f32_16x16x32_bf16(pa0, v4, acc2, 0, 0, 0);
            acc2 = __builtin_amdgcn_mfma_f32_16x16x32_bf16(pa1, v5, acc2, 0, 0, 0);
            acc3 = __builtin_amdgcn_mfma_f32_16x16x32_bf16(pa0, v6, acc3, 0, 0, 0);
            acc3 = __builtin_amdgcn_mfma_f32_16x16x32_bf16(pa1, v7, acc3, 0, 0, 0);
            __builtin_amdgcn_s_setprio(0);

            if (kt < T) stageWrite(lds[cur ^ 1]);
            __syncthreads();
            cur ^= 1;
        }

        den += __shfl_xor(den, 16);
        den += __shfl_xor(den, 32);
        float inv[4];
        #pragma unroll
        for (int r = 0; r < 4; ++r) inv[r] = 1.0f / __shfl(den, lhi * 4 + r);

        float* ob = out + ((size_t)h * 1024 + sigma * 16) * 64;
        #pragma unroll
        for (int r = 0; r < 4; ++r) {
            ob[(lhi * 4 + r) * 64 +  0 + l15] = acc0[r] * inv[r];
            ob[(lhi * 4 + r) * 64 + 16 + l15] = acc1[r] * inv[r];
            ob[(lhi * 4 + r) * 64 + 32 + l15] = acc2[r] * inv[r];
            ob[(lhi * 4 + r) * 64 + 48 + l15] = acc3[r] * inv[r];
        }
    };

    const int s0v = 4 * j + wave;
    runStrip(s0v, j);
    runStrip(63 - s0v, 15 - j);
}

// ---------------------------------------------------------------------------
extern "C" void kernel_launch(void* const* d_in, const int* in_sizes, int n_in,
                              void* d_out, int out_size, void* d_ws, size_t ws_size,
                              hipStream_t stream)
{
    const float* q    = (const float*)d_in[0];
    const float* k    = (const float*)d_in[1];
    const float* v    = (const float*)d_in[2];
    const float* proj = (const float*)d_in[3];
    float* out = (float*)d_out;

    char* ws = (char*)d_ws;
    u16*   qpw  = (u16*)(ws);                                     // 8 MB
    u16*   kpw  = (u16*)(ws + (size_t)8 * 1024 * 1024);           // 8 MB
    u16*   vTw  = (u16*)(ws + (size_t)16 * 1024 * 1024);          // 8 MB
    float* pmax = (float*)(ws + (size_t)24 * 1024 * 1024);        // 2 KB (fused) / 1 KB (R9)
    u16*   ptg  = (u16*)(ws + (size_t)24 * 1024 * 1024 + 4096);   // 8 KB (R9 fallback)

    void* args[] = { (void*)&q, (void*)&k, (void*)&v, (void*)&proj,
                     (void*)&pmax, (void*)&qpw, (void*)&kpw, (void*)&vTw, (void*)&out };
    hipError_t err = hipLaunchCooperativeKernel((const void*)fused, dim3(512), dim3(256),
                                                args, 0, stream);
    if (err != hipSuccess) {
        // deterministic fallback: R9-proven three-kernel path
        hipLaunchKernelGGL(kmax9, dim3(256), dim3(256), 0, stream, k, proj, pmax, ptg);
        hipLaunchKernelGGL(prep9, dim3(768), dim3(256), 0, stream,
                           q, k, v, ptg, pmax, qpw, kpw, vTw);
        hipLaunchKernelGGL(attn9, dim3(512), dim3(256), 0, stream, qpw, kpw, vTw, out);
    }
}

// Round 11
// 41.185 us; speedup vs baseline: 3.8071x; 3.8071x over previous
//
#include <hip/hip_runtime.h>
#include <hip/hip_bf16.h>

// Performer FAVOR+ causal attention, MI355X gfx950.
// B=4 H=16 S=1024 D=64 M=64. fp32 in/out, bf16 MFMA internally.
// R11 = R9 verbatim (proven best, 41.36 us): kmax (256 blk, atomic-free,
// PT dump) + prep (768 blk, register-resident PT) + attn (FROZEN).

#define NRM 0.35355339059327373f   // 64^-0.25
#define EPSF 1e-4f

typedef __attribute__((ext_vector_type(8))) short short8;
typedef __attribute__((ext_vector_type(4))) float f32x4;
typedef __attribute__((ext_vector_type(4))) unsigned uint4v;
typedef unsigned short u16;

__device__ inline u16 f2bf(float f) {
    unsigned u = __float_as_uint(f);
    return (u16)((u + 0x7FFFu + ((u >> 16) & 1u)) >> 16);   // RNE
}
__device__ inline unsigned cvtpk(float lo, float hi) {
    unsigned r; asm("v_cvt_pk_bf16_f32 %0, %1, %2" : "=v"(r) : "v"(lo), "v"(hi)); return r;
}

// ---------------------------------------------------------------------------
// kmax: 256 blocks (4 per head). Block b: partial max of dd = NRM*(k_bf16@P)
// over strips b*16 .. b*16+15 (wave w: 4 strips). Atomic-free. Block 0 also
// dumps the bf16 PT to global (ptg) for prep's register-resident fragments.
// ---------------------------------------------------------------------------
__global__ __launch_bounds__(256) void kmax(
    const float* __restrict__ k, const float* __restrict__ proj,
    float* __restrict__ pmax, u16* __restrict__ ptg)
{
    __shared__ u16 PT[64][72];
    __shared__ float red[4];
    const int tid = threadIdx.x, lane = tid & 63, wave = tid >> 6;
    const int l15 = lane & 15, lhi = lane >> 4;
    const int b = blockIdx.x;   // 0..255

    #pragma unroll
    for (int p = 0; p < 4; ++p) {
        int d = p * 16 + (tid >> 4);
        int m = (tid & 15) * 4;
        float4 pv = *(const float4*)(proj + d * 64 + m);
        PT[m + 0][d] = f2bf(pv.x);
        PT[m + 1][d] = f2bf(pv.y);
        PT[m + 2][d] = f2bf(pv.z);
        PT[m + 3][d] = f2bf(pv.w);
    }
    __syncthreads();

    if (b == 0) {   // dump PT[m][d] (bf16) to global for prep
        const int m = tid >> 2, c0 = (tid & 3) * 16;
        short8 x0 = *(const short8*)&PT[m][c0];
        short8 x1 = *(const short8*)&PT[m][c0 + 8];
        *(short8*)(ptg + m * 64 + c0)     = x0;
        *(short8*)(ptg + m * 64 + c0 + 8) = x1;
    }

    float m2 = -INFINITY;
    for (int i = 0; i < 4; ++i) {
        const int strip = b * 16 + wave * 4 + i;   // 0..4095
        const int row0  = strip * 16;
        const float* xs = k + (size_t)(row0 + l15) * 64 + lhi * 8;
        float4 f0 = *(const float4*)(xs);
        float4 f1 = *(const float4*)(xs + 4);
        float4 f2 = *(const float4*)(xs + 32);
        float4 f3 = *(const float4*)(xs + 36);

        short8 a0, a1;
        a0[0] = (short)f2bf(f0.x); a0[1] = (short)f2bf(f0.y);
        a0[2] = (short)f2bf(f0.z); a0[3] = (short)f2bf(f0.w);
        a0[4] = (short)f2bf(f1.x); a0[5] = (short)f2bf(f1.y);
        a0[6] = (short)f2bf(f1.z); a0[7] = (short)f2bf(f1.w);
        a1[0] = (short)f2bf(f2.x); a1[1] = (short)f2bf(f2.y);
        a1[2] = (short)f2bf(f2.z); a1[3] = (short)f2bf(f2.w);
        a1[4] = (short)f2bf(f3.x); a1[5] = (short)f2bf(f3.y);
        a1[6] = (short)f2bf(f3.z); a1[7] = (short)f2bf(f3.w);

        f32x4 c[4] = { {0,0,0,0}, {0,0,0,0}, {0,0,0,0}, {0,0,0,0} };
        #pragma unroll
        for (int ct = 0; ct < 4; ++ct) {
            short8 b0 = *(const short8*)&PT[ct * 16 + l15][lhi * 8];
            short8 b1 = *(const short8*)&PT[ct * 16 + l15][32 + lhi * 8];
            c[ct] = __builtin_amdgcn_mfma_f32_16x16x32_bf16(a0, b0, c[ct], 0, 0, 0);
            c[ct] = __builtin_amdgcn_mfma_f32_16x16x32_bf16(a1, b1, c[ct], 0, 0, 0);
        }
        #pragma unroll
        for (int ct = 0; ct < 4; ++ct) {
            m2 = fmaxf(m2, fmaxf(fmaxf(c[ct][0], c[ct][1]), fmaxf(c[ct][2], c[ct][3])));
        }
    }
    m2 = fmaxf(m2, __shfl_xor(m2, 1));
    m2 = fmaxf(m2, __shfl_xor(m2, 2));
    m2 = fmaxf(m2, __shfl_xor(m2, 4));
    m2 = fmaxf(m2, __shfl_xor(m2, 8));
    m2 = fmaxf(m2, __shfl_xor(m2, 16));
    m2 = fmaxf(m2, __shfl_xor(m2, 32));
    if (lane == 0) red[wave] = m2 * NRM;
    __syncthreads();
    if (tid == 0)
        pmax[b] = fmaxf(fmaxf(red[0], red[1]), fmaxf(red[2], red[3]));
}

// ---------------------------------------------------------------------------
// prep: 768 blocks. 0..255 q-featmap (4 strips/wave), 256..511 k-featmap
// (4 strips/wave, stab from pmax), 512..767 v transpose (4 tiles/block).
// q/k branches: PT fragments register-resident from ptg — no LDS, no syncs.
// ---------------------------------------------------------------------------
__global__ __launch_bounds__(256) void prep(
    const float* __restrict__ q, const float* __restrict__ k,
    const float* __restrict__ v, const u16* __restrict__ ptg,
    const float* __restrict__ pmax,
    u16* __restrict__ qp, u16* __restrict__ kp, u16* __restrict__ vT)
{
    __shared__ u16 tile[64][72];
    const int tid = threadIdx.x, lane = tid & 63, wave = tid >> 6;
    const int l15 = lane & 15, lhi = lane >> 4;
    const int bid = blockIdx.x;

    if (bid >= 512) {   // ---- v transpose, 4 tiles per block
        const int vb = bid - 512;
        for (int i = 0; i < 4; ++i) {
            const int t = vb * 4 + i;          // 0..1023
            const int bh = t >> 4, s0 = (t & 15) << 6;
            const float* src = v + ((size_t)bh * 1024 + s0) * 64;
            #pragma unroll
            for (int p = 0; p < 4; ++p) {
                int s = p * 16 + (tid >> 4);
                int d = (tid & 15) * 4;
                float4 val = *(const float4*)(src + s * 64 + d);
                tile[d + 0][s] = f2bf(val.x);
                tile[d + 1][s] = f2bf(val.y);
                tile[d + 2][s] = f2bf(val.z);
                tile[d + 3][s] = f2bf(val.w);
            }
            __syncthreads();
            u16* dst = vT + (size_t)bh * 65536 + s0;
            #pragma unroll
            for (int p = 0; p < 4; ++p) {
                int d = p * 16 + (tid >> 4);
                int s = (tid & 15) * 4;
                ushort4 o;
                o.x = tile[d][s]; o.y = tile[d][s + 1];
                o.z = tile[d][s + 2]; o.w = tile[d][s + 3];
                *(ushort4*)(dst + d * 1024 + s) = o;
            }
            __syncthreads();   // WAR: tile reused next iteration
        }
        return;
    }

    // ---- feature map (q or k), PT fragments from global (bit-identical)
    const bool isQ = bid < 256;
    const float* x = isQ ? q : k;
    const int bid2 = bid & 255;

    short8 bf0[4], bf1[4];
    #pragma unroll
    for (int ct = 0; ct < 4; ++ct) {
        const u16* pr = ptg + (ct * 16 + l15) * 64 + lhi * 8;
        bf0[ct] = *(const short8*)(pr);
        bf1[ct] = *(const short8*)(pr + 32);
    }

    float stab = 0.f;
    if (!isQ) {
        const int h = bid2 >> 2;               // 16 strips stay in one head
        const float* pb = pmax + h * 4;
        stab = fmaxf(fmaxf(pb[0], pb[1]), fmaxf(pb[2], pb[3]));
    }

    for (int i = 0; i < 4; ++i) {
        const int strip = bid2 * 16 + wave * 4 + i;   // 0..4095
        const int row0  = strip * 16;

        const float* xs = x + (size_t)(row0 + l15) * 64 + lhi * 8;
        float4 f0 = *(const float4*)(xs);
        float4 f1 = *(const float4*)(xs + 4);
        float4 f2 = *(const float4*)(xs + 32);
        float4 f3 = *(const float4*)(xs + 36);

        short8 a0, a1;
        a0[0] = (short)f2bf(f0.x); a0[1] = (short)f2bf(f0.y);
        a0[2] = (short)f2bf(f0.z); a0[3] = (short)f2bf(f0.w);
        a0[4] = (short)f2bf(f1.x); a0[5] = (short)f2bf(f1.y);
        a0[6] = (short)f2bf(f1.z); a0[7] = (short)f2bf(f1.w);
        a1[0] = (short)f2bf(f2.x); a1[1] = (short)f2bf(f2.y);
        a1[2] = (short)f2bf(f2.z); a1[3] = (short)f2bf(f2.w);
        a1[4] = (short)f2bf(f3.x); a1[5] = (short)f2bf(f3.y);
        a1[6] = (short)f2bf(f3.z); a1[7] = (short)f2bf(f3.w);

        float ss = f0.x*f0.x + f0.y*f0.y + f0.z*f0.z + f0.w*f0.w
                 + f1.x*f1.x + f1.y*f1.y + f1.z*f1.z + f1.w*f1.w
                 + f2.x*f2.x + f2.y*f2.y + f2.z*f2.z + f2.w*f2.w
                 + f3.x*f3.x + f3.y*f3.y + f3.z*f3.z + f3.w*f3.w;
        ss += __shfl_xor(ss, 16);
        ss += __shfl_xor(ss, 32);

        f32x4 c[4] = { {0,0,0,0}, {0,0,0,0}, {0,0,0,0}, {0,0,0,0} };
        #pragma unroll
        for (int ct = 0; ct < 4; ++ct) {
            c[ct] = __builtin_amdgcn_mfma_f32_16x16x32_bf16(a0, bf0[ct], c[ct], 0, 0, 0);
            c[ct] = __builtin_amdgcn_mfma_f32_16x16x32_bf16(a1, bf1[ct], c[ct], 0, 0, 0);
        }

        float diag[4];
        #pragma unroll
        for (int r = 0; r < 4; ++r) diag[r] = __shfl(ss, lhi * 4 + r) * 0.0625f;

        if (isQ) {
            float mx[4];
            #pragma unroll
            for (int r = 0; r < 4; ++r)
                mx[r] = fmaxf(fmaxf(c[0][r], c[1][r]), fmaxf(c[2][r], c[3][r]));
            #pragma unroll
            for (int r = 0; r < 4; ++r) {
                float m = mx[r];
                m = fmaxf(m, __shfl_xor(m, 1));
                m = fmaxf(m, __shfl_xor(m, 2));
                m = fmaxf(m, __shfl_xor(m, 4));
                m = fmaxf(m, __shfl_xor(m, 8));
                mx[r] = m;
            }
            u16* op = qp + (size_t)row0 * 64;
            #pragma unroll
            for (int ct = 0; ct < 4; ++ct) {
                #pragma unroll
                for (int r = 0; r < 4; ++r) {
                    float val = __expf(c[ct][r] * NRM - diag[r] - mx[r] * NRM) + EPSF;
                    op[(lhi * 4 + r) * 64 + ct * 16 + l15] = f2bf(val);
                }
            }
        } else {
            u16* op = kp + (size_t)row0 * 64;
            #pragma unroll
            for (int ct = 0; ct < 4; ++ct) {
                #pragma unroll
                for (int r = 0; r < 4; ++r) {
                    float val = __expf(c[ct][r] * NRM - diag[r] - stab) + EPSF;
                    op[(lhi * 4 + r) * 64 + ct * 16 + l15] = f2bf(val);
                }
            }
        }
    }
}

// ---------------------------------------------------------------------------
// attn: verbatim R3/R5/R7/R8/R9 (proven, FROZEN). 512 blocks x 256 thr.
// ---------------------------------------------------------------------------
__global__ __launch_bounds__(256, 2) void attn(
    const u16* __restrict__ qp, const u16* __restrict__ kp,
    const u16* __restrict__ vT, float* __restrict__ out)
{
    __shared__ char lds[2][16384];   // [buf]: kp tile 8KB | vT tile 8KB

    const int tid = threadIdx.x, lane = tid & 63, wave = tid >> 6;
    const int l15 = lane & 15, lhi = lane >> 4;
    const int x = blockIdx.x;
    const int h = (((x >> 6) << 3)) | (x & 7);   // head: 8 blocks/head on one XCD
    const int j = (x >> 3) & 7;                  // 0..7

    const u16* kph = kp + (size_t)h * 65536;
    const u16* vTh = vT + (size_t)h * 65536;

    // ---- staging assignment: wave 0,1 -> kp chunks 0-3/4-7; wave 2,3 -> vT
    const int rch = lane >> 3;            // row within 8-row chunk
    const int cb  = (lane & 7) * 16;      // col byte within 128B row
    const bool isK = wave < 2;
    const int cbase = (wave & 1) * 4;
    const int gstride = isK ? 4096 : 64;  // elements per kt step

    int lo0, lo1, lo2, lo3;
    const u16 *go0, *go1, *go2, *go3;
    {
        #define STG(cc, LO, GO)                                                 \
        {   int i = cbase + cc; int row = 8 * i + rch;                          \
            int nib = (row & 3) | (((row >> 3) & 1) << 2);                      \
            LO = (isK ? 0 : 8192) + row * 128 + (cb ^ (nib << 4));              \
            GO = isK ? (kph + row * 64 + (cb >> 1))                             \
                     : (vTh + (size_t)row * 1024 + (cb >> 1)); }
        STG(0, lo0, go0) STG(1, lo1, go1) STG(2, lo2, go2) STG(3, lo3, go3)
        #undef STG
    }

    // ---- fragment-read offsets (bytes, swizzled)
    const int rowp = 8 * (l15 >> 2) + (l15 & 3);
    const int nk = (l15 & 3) | (((l15 >> 2) & 1) << 2);
    const int nv = (l15 & 3) | (((l15 >> 3) & 1) << 2);
    const int ok0 = rowp * 128 + ((16 * lhi) ^ (nk << 4));
    const int ok1 = rowp * 128 + ((64 + 16 * lhi) ^ (nk << 4));
    const int ov0 = 8192 + l15 * 128 + ((16 * lhi) ^ (nv << 4));
    const int ov1 = 8192 + l15 * 128 + ((64 + 16 * lhi) ^ (nv << 4));

    short8 ls0, ls1, ls2, ls3;   // staging registers

    auto stageLoad = [&](int kt) {
        ls0 = *(const short8*)(go0 + (size_t)kt * gstride);
        ls1 = *(const short8*)(go1 + (size_t)kt * gstride);
        ls2 = *(const short8*)(go2 + (size_t)kt * gstride);
        ls3 = *(const short8*)(go3 + (size_t)kt * gstride);
    };
    auto stageWrite = [&](char* B) {
        *(short8*)(B + lo0) = ls0;
        *(short8*)(B + lo1) = ls1;
        *(short8*)(B + lo2) = ls2;
        *(short8*)(B + lo3) = ls3;
    };

    auto runStrip = [&](int sigma, int T) {
        const u16* qpr = qp + ((size_t)h * 1024 + sigma * 16 + l15) * 64 + lhi * 8;
        short8 aq0 = *(const short8*)(qpr);
        short8 aq1 = *(const short8*)(qpr + 32);
        const int qrl = ((sigma & 3) << 4) + l15;   // local q-row in diag tile

        f32x4 acc0 = {0,0,0,0}, acc1 = {0,0,0,0}, acc2 = {0,0,0,0}, acc3 = {0,0,0,0};
        float den = 0.f;

        // prologue: stage tile 0 into buf 0
        stageLoad(0);
        stageWrite(lds[0]);
        __syncthreads();

        int cur = 0;
        for (int kt = 0; kt <= T; ++kt) {
            if (kt < T) stageLoad(kt + 1);

            const char* B = lds[cur];
            short8 k0 = *(const short8*)(B + ok0);
            short8 k1 = *(const short8*)(B + ok1);
            short8 k2 = *(const short8*)(B + ok0 + 512);
            short8 k3 = *(const short8*)(B + ok1 + 512);
            short8 k4 = *(const short8*)(B + ok0 + 4096);
            short8 k5 = *(const short8*)(B + ok1 + 4096);
            short8 k6 = *(const short8*)(B + ok0 + 4608);
            short8 k7 = *(const short8*)(B + ok1 + 4608);
            short8 v0 = *(const short8*)(B + ov0);
            short8 v1 = *(const short8*)(B + ov1);
            short8 v2 = *(const short8*)(B + ov0 + 2048);
            short8 v3 = *(const short8*)(B + ov1 + 2048);
            short8 v4 = *(const short8*)(B + ov0 + 4096);
            short8 v5 = *(const short8*)(B + ov1 + 4096);
            short8 v6 = *(const short8*)(B + ov0 + 6144);
            short8 v7 = *(const short8*)(B + ov1 + 6144);

            f32x4 s0 = {0,0,0,0}, s1 = {0,0,0,0}, s2 = {0,0,0,0}, s3 = {0,0,0,0};
            __builtin_amdgcn_s_setprio(1);
            s0 = __builtin_amdgcn_mfma_f32_16x16x32_bf16(k0, aq0, s0, 0, 0, 0);
            s0 = __builtin_amdgcn_mfma_f32_16x16x32_bf16(k1, aq1, s0, 0, 0, 0);
            s1 = __builtin_amdgcn_mfma_f32_16x16x32_bf16(k2, aq0, s1, 0, 0, 0);
            s1 = __builtin_amdgcn_mfma_f32_16x16x32_bf16(k3, aq1, s1, 0, 0, 0);
            s2 = __builtin_amdgcn_mfma_f32_16x16x32_bf16(k4, aq0, s2, 0, 0, 0);
            s2 = __builtin_amdgcn_mfma_f32_16x16x32_bf16(k5, aq1, s2, 0, 0, 0);
            s3 = __builtin_amdgcn_mfma_f32_16x16x32_bf16(k6, aq0, s3, 0, 0, 0);
            s3 = __builtin_amdgcn_mfma_f32_16x16x32_bf16(k7, aq1, s3, 0, 0, 0);
            __builtin_amdgcn_s_setprio(0);

            if (kt == T) {   // diagonal-tile causal mask
                const int kc = 8 * lhi;
                #pragma unroll
                for (int r = 0; r < 4; ++r) {
                    if (kc + r      > qrl) s0[r] = 0.f;
                    if (kc + 4 + r  > qrl) s1[r] = 0.f;
                    if (kc + 32 + r > qrl) s2[r] = 0.f;
                    if (kc + 36 + r > qrl) s3[r] = 0.f;
                }
            }
            float t0 = (s0[0] + s0[1]) + (s0[2] + s0[3]);
            float t1 = (s1[0] + s1[1]) + (s1[2] + s1[3]);
            float t2 = (s2[0] + s2[1]) + (s2[2] + s2[3]);
            float t3 = (s3[0] + s3[1]) + (s3[2] + s3[3]);
            den += (t0 + t1) + (t2 + t3);

            uint4v w0 = { cvtpk(s0[0], s0[1]), cvtpk(s0[2], s0[3]),
                          cvtpk(s1[0], s1[1]), cvtpk(s1[2], s1[3]) };
            uint4v w1 = { cvtpk(s2[0], s2[1]), cvtpk(s2[2], s2[3]),
                          cvtpk(s3[0], s3[1]), cvtpk(s3[2], s3[3]) };
            short8 pa0 = __builtin_bit_cast(short8, w0);
            short8 pa1 = __builtin_bit_cast(short8, w1);

            __builtin_amdgcn_s_setprio(1);
            acc0 = __builtin_amdgcn_mfma_f32_16x16x32_bf16(pa0, v0, acc0, 0, 0, 0);
            acc0 = __builtin_amdgcn_mfma_f32_16x16x32_bf16(pa1, v1, acc0, 0, 0, 0);
            acc1 = __builtin_amdgcn_mfma_f32_16x16x32_bf16(pa0, v2, acc1, 0, 0, 0);
            acc1 = __builtin_amdgcn_mfma_f32_16x16x32_bf16(pa1, v3, acc1, 0, 0, 0);
            acc2 = __builtin_amdgcn_mfma_f32_16x16x32_bf16(pa0, v4, acc2, 0, 0, 0);
            acc2 = __builtin_amdgcn_mfma_f32_16x16x32_bf16(pa1, v5, acc2, 0, 0, 0);
            acc3 = __builtin_amdgcn_mfma_f32_16x16x32_bf16(pa0, v6, acc3, 0, 0, 0);
            acc3 = __builtin_amdgcn_mfma_f32_16x16x32_bf16(pa1, v7, acc3, 0, 0, 0);
            __builtin_amdgcn_s_setprio(0);

            if (kt < T) stageWrite(lds[cur ^ 1]);   // vmcnt wait lands here
            __syncthreads();
            cur ^= 1;
        }

        den += __shfl_xor(den, 16);
        den += __shfl_xor(den, 32);
        float inv[4];
        #pragma unroll
        for (int r = 0; r < 4; ++r) inv[r] = 1.0f / __shfl(den, lhi * 4 + r);

        float* ob = out + ((size_t)h * 1024 + sigma * 16) * 64;
        #pragma unroll
        for (int r = 0; r < 4; ++r) {
            ob[(lhi * 4 + r) * 64 +  0 + l15] = acc0[r] * inv[r];
            ob[(lhi * 4 + r) * 64 + 16 + l15] = acc1[r] * inv[r];
            ob[(lhi * 4 + r) * 64 + 32 + l15] = acc2[r] * inv[r];
            ob[(lhi * 4 + r) * 64 + 48 + l15] = acc3[r] * inv[r];
        }
    };

    const int s0v = 4 * j + wave;     // 0..31, T = j (uniform in block)
    runStrip(s0v, j);
    runStrip(63 - s0v, 15 - j);       // T = 15-j (uniform in block)
}

// ---------------------------------------------------------------------------
extern "C" void kernel_launch(void* const* d_in, const int* in_sizes, int n_in,
                              void* d_out, int out_size, void* d_ws, size_t ws_size,
                              hipStream_t stream)
{
    const float* q    = (const float*)d_in[0];
    const float* k    = (const float*)d_in[1];
    const float* v    = (const float*)d_in[2];
    const float* proj = (const float*)d_in[3];
    float* out = (float*)d_out;

    char* ws = (char*)d_ws;
    u16*   qpw  = (u16*)(ws);                                     // 8 MB
    u16*   kpw  = (u16*)(ws + (size_t)8 * 1024 * 1024);           // 8 MB
    u16*   vTw  = (u16*)(ws + (size_t)16 * 1024 * 1024);          // 8 MB
    float* pmax = (float*)(ws + (size_t)24 * 1024 * 1024);        // 1 KB
    u16*   ptg  = (u16*)(ws + (size_t)24 * 1024 * 1024 + 4096);   // 8 KB

    hipLaunchKernelGGL(kmax, dim3(256), dim3(256), 0, stream, k, proj, pmax, ptg);
    hipLaunchKernelGGL(prep, dim3(768), dim3(256), 0, stream,
                       q, k, v, ptg, pmax, qpw, kpw, vTw);
    hipLaunchKernelGGL(attn, dim3(512), dim3(256), 0, stream, qpw, kpw, vTw, out);
}